// Round 22
// baseline (409.420 us; speedup 1.0000x reference)
//
#include <hip/hip_runtime.h>
#include <math.h>

#define NIMG 128
#define HW   256
#define NPX  (HW*HW)
#define NBLK (NIMG*16*2)   // 4096 blocks: (img, strip, combo-half)

typedef float f32x4 __attribute__((ext_vector_type(4)));
typedef short bf16x8 __attribute__((ext_vector_type(8)));

__device__ __forceinline__ int refl_idx(int t) {
  return t < 0 ? -t : (t > 255 ? 510 - t : t);
}
__device__ __forceinline__ unsigned int bf16_rtn(float f) {
  unsigned int u = __float_as_uint(f);
  return (u + 0x7fffu + ((u >> 16) & 1u)) >> 16;
}
__device__ __forceinline__ unsigned int rtn_pack(float a, float b) {
  return bf16_rtn(a) | (bf16_rtn(b) << 16);
}
__device__ __forceinline__ unsigned int rhu_pack(float a, float b) {
  return ((__float_as_uint(a) + 0x8000u) >> 16) |
         ((__float_as_uint(b) + 0x8000u) & 0xffff0000u);
}

// ---------------- Kernel A: per-image mean / inv_std (ddof=1) ----------------
__global__ __launch_bounds__(256)
void stats_kernel(const float* __restrict__ pred, const float* __restrict__ targ,
                  float* __restrict__ stats)
{
  const int b = blockIdx.x;
  const int which = b >> 7;
  const int img = b & 127;
  const float4* src = (const float4*)((which ? targ : pred) + (size_t)img * NPX);
  const int t = threadIdx.x;
  double s = 0.0, s2 = 0.0;
  for (int i = t; i < NPX/4; i += 256) {
    float4 v = src[i];
    s  += (double)v.x + (double)v.y + (double)v.z + (double)v.w;
    s2 += (double)v.x*v.x + (double)v.y*v.y + (double)v.z*v.z + (double)v.w*v.w;
  }
  __shared__ double rs[256], rs2[256];
  rs[t] = s; rs2[t] = s2;
  __syncthreads();
  for (int off = 128; off > 0; off >>= 1) {
    if (t < off) { rs[t] += rs[t+off]; rs2[t] += rs2[t+off]; }
    __syncthreads();
  }
  if (t == 0) {
    const double n = (double)NPX;
    double mean = rs[0] / n;
    double var = (rs2[0] - n*mean*mean) / (n - 1.0);
    stats[(which*NIMG + img)*2 + 0] = (float)mean;
    stats[(which*NIMG + img)*2 + 1] = (float)(1.0 / sqrt(var));
  }
}

// ---------------- Fused SSIM kernel ----------------
// Block = (img, 16-row strip, half of the 25 combos). 512 threads = 8 waves.
// Single XOR-swizzled vfT (round-19 layout), 2 barriers/combo, gwfrag table
// for the block's 13 combos. LDS 65.3 KB -> 2 independent blocks/CU so one
// block's compute covers the other's barrier drain (round-19 was 1x1024thr
// = whole-CU barrier drains; no pipe >71%).
struct SMEM {
  unsigned int  vfT[12800];          // 51200 B: [f*2560 + m*160 + q] ^ x
  unsigned int  gwfrag[13][64][4];   // 13312 B (block's combos)
  unsigned short gwb[25][16];        //   800 B
};

__global__ __launch_bounds__(512, 4)
void ssim_fused(const float* __restrict__ pred, const float* __restrict__ targ,
                const float* __restrict__ stats, float* __restrict__ partial)
{
  __shared__ SMEM sm;
  const int bid = blockIdx.x;
  const int img = bid >> 5;
  const int strip = (bid >> 1) & 15;
  const int half = bid & 1;
  const int c0 = half ? 13 : 0;
  const int c1 = half ? 25 : 13;
  const int R0 = strip * 16;
  const int t = threadIdx.x;
  const int lane = t & 63, wid = t >> 6;   // 8 waves
  const int g = lane >> 4;        // k-group 0..3
  const int mrow = lane & 15;     // A-row / B-col lane index
  const int swz = 4 * (mrow & 7); // XOR swizzle for this lane's vfT row

  // --- phase 0: gaussian taps (all 25 combos; double math, numpy-matching) ---
  if (t < 400) {
    const int c = t >> 4, tap = t & 15;
    const int ksi = c / 5, si = c % 5;
    const int ks = 5 + 2*ksi, PAD = 2 + ksi;
    const double sig = (si==0)?0.8:(si==1)?1.2:(si==2)?1.5:(si==3)?1.8:2.0;
    unsigned short w = 0;
    if (tap < ks) {
      double sum = 0.0, mine = 0.0;
      for (int a = 0; a < ks; ++a) {
        double d = (double)(a - PAD) / sig;
        double e = exp(-0.5 * d * d);
        sum += e;
        if (a == tap) mine = e;
      }
      w = (unsigned short)bf16_rtn((float)(mine / sum));
    }
    sm.gwb[c][tap] = w;
  }
  // zero u32 q=139 (slots 278/279) of every (field, row): read by the ht=15
  // b128 with zero weight; must be non-NaN. Swizzle-aware address.
  if (t < 80) {
    const int f = t >> 4, m = t & 15;
    sm.vfT[(f*2560 + m*160 + 139) ^ (4*(m & 7))] = 0;
  }
  __syncthreads();

  // --- phase 0b: per-lane weight fragments for THIS block's combos ---
  const int ncb = c1 - c0;
  for (int e = t; e < ncb*64; e += 512) {
    const int ci = e >> 6, l = e & 63;
    const int c = c0 + ci;
    const int gg = l >> 4, mr = l & 15;
    const int PAD = 2 + c / 5;
    #pragma unroll
    for (int j2 = 0; j2 < 4; ++j2) {
      const int d0 = gg*8 + 2*j2 - mr - 6 + PAD;
      const unsigned int w0 = ((unsigned)d0 < 16u) ? (unsigned)sm.gwb[c][d0] : 0u;
      const unsigned int w1 = ((unsigned)(d0+1) < 16u) ? (unsigned)sm.gwb[c][d0+1] : 0u;
      sm.gwfrag[ci][l][j2] = w0 | (w1 << 16);
    }
  }

  // --- phase 1: hoist vertical field fragments into registers (once) ---
  const float mx  = stats[img*2 + 0];
  const float ixv = stats[img*2 + 1];
  const float my  = stats[(NIMG + img)*2 + 0];
  const float iyv = stats[(NIMG + img)*2 + 1];
  const float* pp = pred + (size_t)img * NPX;
  const float* tp = targ + (size_t)img * NPX;

  union UF { unsigned int w[4]; bf16x8 v; };
  UF aX{}, aY{}, aXX{}, aYY{}, aXY{};   // tile tau = wid
  UF cX{}, cY{}, cXX{}, cYY{}, cXY{};   // tile tau = wid+8
  UF b1{};                              // tile tau = 16, field = wid (waves 0..4)

  auto stage_tile = [&](int tau, UF& fx, UF& fy, UF& fxx, UF& fyy, UF& fxy) {
    const int ci = refl_idx(tau*16 + mrow - 8);
    #pragma unroll
    for (int j2 = 0; j2 < 4; ++j2) {
      const int k0  = 8*g + 2*j2;
      const int ar0 = refl_idx(R0 - 6 + k0);
      const int ar1 = refl_idx(R0 - 5 + k0);
      const float p0 = pp[ar0*HW + ci], p1 = pp[ar1*HW + ci];
      const float q0 = tp[ar0*HW + ci], q1 = tp[ar1*HW + ci];
      const float xa = (p0 - mx)*ixv, xb = (p1 - mx)*ixv;
      const float ya = (q0 - my)*iyv, yb = (q1 - my)*iyv;
      fx.w[j2]  = rtn_pack(xa, xb);
      fy.w[j2]  = rtn_pack(ya, yb);
      fxx.w[j2] = rhu_pack(xa*xa, xb*xb);
      fyy.w[j2] = rhu_pack(ya*ya, yb*yb);
      fxy.w[j2] = rhu_pack(xa*ya, xb*yb);
    }
  };
  stage_tile(wid,     aX, aY, aXX, aYY, aXY);
  stage_tile(wid + 8, cX, cY, cXX, cYY, cXY);
  if (wid < 5) {
    UF tX{}, tY{}, tXX{}, tYY{}, tXY{};
    stage_tile(16, tX, tY, tXX, tYY, tXY);
    switch (wid) {
      case 0:  b1 = tX;  break;
      case 1:  b1 = tY;  break;
      case 2:  b1 = tXX; break;
      case 3:  b1 = tYY; break;
      default: b1 = tXY; break;
    }
  }

  const f32x4 zero4 = {0.f, 0.f, 0.f, 0.f};
  const float C1f = 1e-4f, C2f = 9e-4f;
  float acc_total = 0.f;
  const int r = R0 + mrow;
  const int rowbase = mrow * 160;

  // vertical tile (TRANSPOSED: field as A, W as B): lane holds row=mrow,
  // 4 consecutive cols -> 2 x b32 write per field at swizzled addresses.
  auto vert_tile = [&](const UF& fX, const UF& fY, const UF& fXX, const UF& fYY,
                       const UF& fXY, int tau, const bf16x8& wfrag) {
    const int q0 = 8*tau + 2*g + 3;   // slot (16*tau+4g+6)/2; valid for tau=16 too
    f32x4 dx  = __builtin_amdgcn_mfma_f32_16x16x32_bf16(fX.v,  wfrag, zero4, 0,0,0);
    f32x4 dy  = __builtin_amdgcn_mfma_f32_16x16x32_bf16(fY.v,  wfrag, zero4, 0,0,0);
    f32x4 dxx = __builtin_amdgcn_mfma_f32_16x16x32_bf16(fXX.v, wfrag, zero4, 0,0,0);
    f32x4 dyy = __builtin_amdgcn_mfma_f32_16x16x32_bf16(fYY.v, wfrag, zero4, 0,0,0);
    f32x4 dxy = __builtin_amdgcn_mfma_f32_16x16x32_bf16(fXY.v, wfrag, zero4, 0,0,0);
    const int b0 = rowbase + q0;
    sm.vfT[(0*2560 + b0) ^ swz]     = rhu_pack(dx[0], dx[1]);
    sm.vfT[(0*2560 + b0 + 1) ^ swz] = rhu_pack(dx[2], dx[3]);
    sm.vfT[(1*2560 + b0) ^ swz]     = rhu_pack(dy[0], dy[1]);
    sm.vfT[(1*2560 + b0 + 1) ^ swz] = rhu_pack(dy[2], dy[3]);
    sm.vfT[(2*2560 + b0) ^ swz]     = rhu_pack(dxx[0], dxx[1]);
    sm.vfT[(2*2560 + b0 + 1) ^ swz] = rhu_pack(dxx[2], dxx[3]);
    sm.vfT[(3*2560 + b0) ^ swz]     = rhu_pack(dyy[0], dyy[1]);
    sm.vfT[(3*2560 + b0 + 1) ^ swz] = rhu_pack(dyy[2], dyy[3]);
    sm.vfT[(4*2560 + b0) ^ swz]     = rhu_pack(dxy[0], dxy[1]);
    sm.vfT[(4*2560 + b0 + 1) ^ swz] = rhu_pack(dxy[2], dxy[3]);
  };

  __syncthreads();   // gwfrag visible

  for (int cb = c0; cb < c1; ++cb) {
    const int ci = cb - c0;
    const int PAD = 2 + cb/5;

    UF frag;
    *(uint4*)frag.w = *(const uint4*)&sm.gwfrag[ci][lane][0];

    // vertical: tiles wid and wid+8 (all waves) + tile 16 (field wid, waves 0..4)
    vert_tile(aX, aY, aXX, aYY, aXY, wid,     frag.v);
    vert_tile(cX, cY, cXX, cYY, cXY, wid + 8, frag.v);
    if (wid < 5) {
      const int q0 = 131 + 2*g;
      f32x4 d = __builtin_amdgcn_mfma_f32_16x16x32_bf16(b1.v, frag.v, zero4, 0,0,0);
      const int b0 = rowbase + q0;
      sm.vfT[(wid*2560 + b0) ^ swz]     = rhu_pack(d[0], d[1]);
      sm.vfT[(wid*2560 + b0 + 1) ^ swz] = rhu_pack(d[2], d[3]);
    }
    __syncthreads();   // vfT writes visible

    // horizontal + smap: tiles ht = wid and wid+8; 5 x b128 each
    const bool rok = (r >= PAD) && (r < HW - PAD);
    float accc = 0.f;
    #pragma unroll
    for (int hh = 0; hh < 2; ++hh) {
      const int ht = wid + hh*8;
      const int C0 = ht*16;
      const int qb = rowbase + ht*8 + 4 + 4*g;   // 16B-aligned pre-swizzle
      UF bx, by, bxx, byy, bxy;
      *(uint4*)bx.w  = *(const uint4*)&sm.vfT[(0*2560 + qb) ^ swz];
      *(uint4*)by.w  = *(const uint4*)&sm.vfT[(1*2560 + qb) ^ swz];
      *(uint4*)bxx.w = *(const uint4*)&sm.vfT[(2*2560 + qb) ^ swz];
      *(uint4*)byy.w = *(const uint4*)&sm.vfT[(3*2560 + qb) ^ swz];
      *(uint4*)bxy.w = *(const uint4*)&sm.vfT[(4*2560 + qb) ^ swz];
      f32x4 dhx  = __builtin_amdgcn_mfma_f32_16x16x32_bf16(frag.v, bx.v,  zero4, 0,0,0);
      f32x4 dhy  = __builtin_amdgcn_mfma_f32_16x16x32_bf16(frag.v, by.v,  zero4, 0,0,0);
      f32x4 dhxx = __builtin_amdgcn_mfma_f32_16x16x32_bf16(frag.v, bxx.v, zero4, 0,0,0);
      f32x4 dhyy = __builtin_amdgcn_mfma_f32_16x16x32_bf16(frag.v, byy.v, zero4, 0,0,0);
      f32x4 dhxy = __builtin_amdgcn_mfma_f32_16x16x32_bf16(frag.v, bxy.v, zero4, 0,0,0);
      #pragma unroll
      for (int i = 0; i < 4; ++i) {
        const int c = C0 + g*4 + i;
        if (rok && c >= PAD && c < HW - PAD) {
          const float hx = dhx[i], hy = dhy[i];
          const float hxx = dhxx[i], hyy = dhyy[i], hxy = dhxy[i];
          const float sx = hxx - hx*hx, sy = hyy - hy*hy, sxy = hxy - hx*hy;
          const float num = (2.f*hx*hy + C1f) * (2.f*sxy + C2f);
          const float den = (hx*hx + hy*hy + C1f) * (sx + sy + C2f);
          accc += num * __builtin_amdgcn_rcpf(den);
        }
      }
    }
    const float n1 = (float)(HW - 2*PAD);
    acc_total += accc * __builtin_amdgcn_rcpf(n1 * n1);

    __syncthreads();   // readers done before next combo's vfT writes
  }

  // block reduction (red aliases vfT; all vfT reads are done)
  float* red = (float*)sm.vfT;
  red[t] = acc_total;
  __syncthreads();
  for (int off = 256; off > 0; off >>= 1) {
    if (t < off) red[t] += red[t+off];
    __syncthreads();
  }
  if (t == 0) partial[bid] = red[0] * (1.f / (25.f * 128.f));
}

// ---------------- Kernel C: final deterministic reduction ----------------
__global__ __launch_bounds__(256)
void reduce_kernel(const float* __restrict__ partial, float* __restrict__ out)
{
  const int t = threadIdx.x;
  double s = 0.0;
  for (int i = t; i < NBLK; i += 256) s += (double)partial[i];
  __shared__ double red[256];
  red[t] = s;
  __syncthreads();
  for (int off = 128; off > 0; off >>= 1) {
    if (t < off) red[t] += red[t+off];
    __syncthreads();
  }
  if (t == 0) out[0] = (float)(0.5 - 0.5 * red[0]);
}

extern "C" void kernel_launch(void* const* d_in, const int* in_sizes, int n_in,
                              void* d_out, int out_size, void* d_ws, size_t ws_size,
                              hipStream_t stream) {
  const float* pred = (const float*)d_in[0];
  const float* targ = (const float*)d_in[1];
  float* out = (float*)d_out;
  float* ws = (float*)d_ws;
  float* stats   = ws;          // 512 floats
  float* partial = ws + 512;    // NBLK floats

  stats_kernel<<<256, 256, 0, stream>>>(pred, targ, stats);
  ssim_fused<<<NBLK, 512, 0, stream>>>(pred, targ, stats, partial);
  reduce_kernel<<<1, 256, 0, stream>>>(partial, out);
}

// Round 23
// 338.052 us; speedup vs baseline: 1.2111x; 1.2111x over previous
//
#include <hip/hip_runtime.h>
#include <math.h>

#define NIMG 128
#define HW   256
#define NPX  (HW*HW)
#define NBLK (NIMG*16)   // 2048 blocks: (img, strip)

typedef float f32x4 __attribute__((ext_vector_type(4)));
typedef short bf16x8 __attribute__((ext_vector_type(8)));

__device__ __forceinline__ int refl_idx(int t) {
  return t < 0 ? -t : (t > 255 ? 510 - t : t);
}
__device__ __forceinline__ unsigned int bf16_rtn(float f) {
  unsigned int u = __float_as_uint(f);
  return (u + 0x7fffu + ((u >> 16) & 1u)) >> 16;
}
__device__ __forceinline__ unsigned int rtn_pack(float a, float b) {
  return bf16_rtn(a) | (bf16_rtn(b) << 16);
}
__device__ __forceinline__ unsigned int rhu_pack(float a, float b) {
  return ((__float_as_uint(a) + 0x8000u) >> 16) |
         ((__float_as_uint(b) + 0x8000u) & 0xffff0000u);
}

// ---------------- Kernel A: per-image mean / inv_std (ddof=1) ----------------
__global__ __launch_bounds__(256)
void stats_kernel(const float* __restrict__ pred, const float* __restrict__ targ,
                  float* __restrict__ stats)
{
  const int b = blockIdx.x;
  const int which = b >> 7;
  const int img = b & 127;
  const float4* src = (const float4*)((which ? targ : pred) + (size_t)img * NPX);
  const int t = threadIdx.x;
  double s = 0.0, s2 = 0.0;
  for (int i = t; i < NPX/4; i += 256) {
    float4 v = src[i];
    s  += (double)v.x + (double)v.y + (double)v.z + (double)v.w;
    s2 += (double)v.x*v.x + (double)v.y*v.y + (double)v.z*v.z + (double)v.w*v.w;
  }
  __shared__ double rs[256], rs2[256];
  rs[t] = s; rs2[t] = s2;
  __syncthreads();
  for (int off = 128; off > 0; off >>= 1) {
    if (t < off) { rs[t] += rs[t+off]; rs2[t] += rs2[t+off]; }
    __syncthreads();
  }
  if (t == 0) {
    const double n = (double)NPX;
    double mean = rs[0] / n;
    double var = (rs2[0] - n*mean*mean) / (n - 1.0);
    stats[(which*NIMG + img)*2 + 0] = (float)mean;
    stats[(which*NIMG + img)*2 + 1] = (float)(1.0 / sqrt(var));
  }
}

// ---------------- Fused SSIM kernel: all 25 combos per block ----------------
// Block = (img, 16-row strip). 1024 threads = 16 waves. Best verified
// configuration (round 19, 338 us): XOR-swizzled vfT (u32 units, row stride
// 160, slot +6 -> horizontal B = 5 x ds_read_b128), register-hoisted
// vertical field fragments, transposed vertical MFMA (2 x b32 writes/field),
// prebuilt gwfrag table (1 b128/combo), double-buffered vfT with ONE
// barrier per combo.
struct SMEM {
  unsigned int  vfT[2][12800];       // 2 x 51200 B: [f*2560 + m*160 + q] ^ x
  unsigned int  gwfrag[25][64][4];   // 25600 B
  unsigned short gwb[25][16];        //   800 B
  float red[1024];                   //  4096 B
};

__global__ __launch_bounds__(1024, 4)
void ssim_fused(const float* __restrict__ pred, const float* __restrict__ targ,
                const float* __restrict__ stats, float* __restrict__ partial)
{
  __shared__ SMEM sm;
  const int bid = blockIdx.x;
  const int img = bid >> 4, strip = bid & 15;
  const int R0 = strip * 16;
  const int t = threadIdx.x;
  const int lane = t & 63, wid = t >> 6;   // 16 waves
  const int g = lane >> 4;        // k-group 0..3
  const int mrow = lane & 15;     // A-row / B-col lane index
  const int swz = 4 * (mrow & 7); // XOR swizzle for this lane's vfT row

  // --- phase 0: gaussian taps per combo (double math, numpy-matching) ---
  if (t < 400) {
    const int c = t >> 4, tap = t & 15;
    const int ksi = c / 5, si = c % 5;
    const int ks = 5 + 2*ksi, PAD = 2 + ksi;
    const double sig = (si==0)?0.8:(si==1)?1.2:(si==2)?1.5:(si==3)?1.8:2.0;
    unsigned short w = 0;
    if (tap < ks) {
      double sum = 0.0, mine = 0.0;
      for (int a = 0; a < ks; ++a) {
        double d = (double)(a - PAD) / sig;
        double e = exp(-0.5 * d * d);
        sum += e;
        if (a == tap) mine = e;
      }
      w = (unsigned short)bf16_rtn((float)(mine / sum));
    }
    sm.gwb[c][tap] = w;
  }
  // zero u32 q=139 (slots 278/279) of every (buf, field, row): read by the
  // ht=15 b128 with zero weight; must be non-NaN. Swizzle-aware address.
  if (t < 160) {
    const int b = t / 80, rem = t % 80;
    const int f = rem >> 4, m = rem & 15;
    sm.vfT[b][(f*2560 + m*160 + 139) ^ (4*(m & 7))] = 0;
  }
  __syncthreads();

  // --- phase 0b: build per-lane weight fragments for all 25 combos ---
  for (int e = t; e < 1600; e += 1024) {
    const int c = e >> 6, l = e & 63;
    const int gg = l >> 4, mr = l & 15;
    const int PAD = 2 + c / 5;
    #pragma unroll
    for (int j2 = 0; j2 < 4; ++j2) {
      const int d0 = gg*8 + 2*j2 - mr - 6 + PAD;
      const unsigned int w0 = ((unsigned)d0 < 16u) ? (unsigned)sm.gwb[c][d0] : 0u;
      const unsigned int w1 = ((unsigned)(d0+1) < 16u) ? (unsigned)sm.gwb[c][d0+1] : 0u;
      sm.gwfrag[c][l][j2] = w0 | (w1 << 16);
    }
  }

  // --- phase 1: hoist vertical field fragments into registers (once) ---
  const float mx  = stats[img*2 + 0];
  const float ixv = stats[img*2 + 1];
  const float my  = stats[(NIMG + img)*2 + 0];
  const float iyv = stats[(NIMG + img)*2 + 1];
  const float* pp = pred + (size_t)img * NPX;
  const float* tp = targ + (size_t)img * NPX;

  union UF { unsigned int w[4]; bf16x8 v; };
  UF aX{}, aY{}, aXX{}, aYY{}, aXY{};   // tile tau = wid  (all waves)
  UF bX{}, bY{}, bXX{}, bYY{}, bXY{};   // tile tau = 16   (wave 0 only)

  auto stage_tile = [&](int tau, UF& fx, UF& fy, UF& fxx, UF& fyy, UF& fxy) {
    const int ci = refl_idx(tau*16 + mrow - 8);
    #pragma unroll
    for (int j2 = 0; j2 < 4; ++j2) {
      const int k0  = 8*g + 2*j2;
      const int ar0 = refl_idx(R0 - 6 + k0);
      const int ar1 = refl_idx(R0 - 5 + k0);
      const float p0 = pp[ar0*HW + ci], p1 = pp[ar1*HW + ci];
      const float q0 = tp[ar0*HW + ci], q1 = tp[ar1*HW + ci];
      const float xa = (p0 - mx)*ixv, xb = (p1 - mx)*ixv;
      const float ya = (q0 - my)*iyv, yb = (q1 - my)*iyv;
      fx.w[j2]  = rtn_pack(xa, xb);
      fy.w[j2]  = rtn_pack(ya, yb);
      fxx.w[j2] = rhu_pack(xa*xa, xb*xb);
      fyy.w[j2] = rhu_pack(ya*ya, yb*yb);
      fxy.w[j2] = rhu_pack(xa*ya, xb*yb);
    }
  };
  stage_tile(wid, aX, aY, aXX, aYY, aXY);
  if (wid == 0) stage_tile(16, bX, bY, bXX, bYY, bXY);

  const f32x4 zero4 = {0.f, 0.f, 0.f, 0.f};
  const float C1f = 1e-4f, C2f = 9e-4f;
  float acc_total = 0.f;
  const int r = R0 + mrow;
  const int rowbase = mrow * 160;

  // vertical pass (TRANSPOSED: field as A, W as B): lane holds row=mrow,
  // 4 consecutive cols -> 2 x b32 write per field at swizzled addresses.
  auto vert = [&](const bf16x8& wfrag, unsigned int* dst) {
    {
      const int q0 = 8*wid + 2*g + 3;   // slot (vc0+6)/2, vc0 = 16*wid+4*g
      f32x4 dx  = __builtin_amdgcn_mfma_f32_16x16x32_bf16(aX.v,  wfrag, zero4, 0,0,0);
      f32x4 dy  = __builtin_amdgcn_mfma_f32_16x16x32_bf16(aY.v,  wfrag, zero4, 0,0,0);
      f32x4 dxx = __builtin_amdgcn_mfma_f32_16x16x32_bf16(aXX.v, wfrag, zero4, 0,0,0);
      f32x4 dyy = __builtin_amdgcn_mfma_f32_16x16x32_bf16(aYY.v, wfrag, zero4, 0,0,0);
      f32x4 dxy = __builtin_amdgcn_mfma_f32_16x16x32_bf16(aXY.v, wfrag, zero4, 0,0,0);
      const int b0 = rowbase + q0;
      dst[(0*2560 + b0) ^ swz]     = rhu_pack(dx[0], dx[1]);
      dst[(0*2560 + b0 + 1) ^ swz] = rhu_pack(dx[2], dx[3]);
      dst[(1*2560 + b0) ^ swz]     = rhu_pack(dy[0], dy[1]);
      dst[(1*2560 + b0 + 1) ^ swz] = rhu_pack(dy[2], dy[3]);
      dst[(2*2560 + b0) ^ swz]     = rhu_pack(dxx[0], dxx[1]);
      dst[(2*2560 + b0 + 1) ^ swz] = rhu_pack(dxx[2], dxx[3]);
      dst[(3*2560 + b0) ^ swz]     = rhu_pack(dyy[0], dyy[1]);
      dst[(3*2560 + b0 + 1) ^ swz] = rhu_pack(dyy[2], dyy[3]);
      dst[(4*2560 + b0) ^ swz]     = rhu_pack(dxy[0], dxy[1]);
      dst[(4*2560 + b0 + 1) ^ swz] = rhu_pack(dxy[2], dxy[3]);
    }
    if (wid == 0) {   // 17th tile (slots for vc0 = 256+4g)
      const int q0 = 131 + 2*g;
      f32x4 dx  = __builtin_amdgcn_mfma_f32_16x16x32_bf16(bX.v,  wfrag, zero4, 0,0,0);
      f32x4 dy  = __builtin_amdgcn_mfma_f32_16x16x32_bf16(bY.v,  wfrag, zero4, 0,0,0);
      f32x4 dxx = __builtin_amdgcn_mfma_f32_16x16x32_bf16(bXX.v, wfrag, zero4, 0,0,0);
      f32x4 dyy = __builtin_amdgcn_mfma_f32_16x16x32_bf16(bYY.v, wfrag, zero4, 0,0,0);
      f32x4 dxy = __builtin_amdgcn_mfma_f32_16x16x32_bf16(bXY.v, wfrag, zero4, 0,0,0);
      const int b0 = rowbase + q0;
      dst[(0*2560 + b0) ^ swz]     = rhu_pack(dx[0], dx[1]);
      dst[(0*2560 + b0 + 1) ^ swz] = rhu_pack(dx[2], dx[3]);
      dst[(1*2560 + b0) ^ swz]     = rhu_pack(dy[0], dy[1]);
      dst[(1*2560 + b0 + 1) ^ swz] = rhu_pack(dy[2], dy[3]);
      dst[(2*2560 + b0) ^ swz]     = rhu_pack(dxx[0], dxx[1]);
      dst[(2*2560 + b0 + 1) ^ swz] = rhu_pack(dxx[2], dxx[3]);
      dst[(3*2560 + b0) ^ swz]     = rhu_pack(dyy[0], dyy[1]);
      dst[(3*2560 + b0 + 1) ^ swz] = rhu_pack(dyy[2], dyy[3]);
      dst[(4*2560 + b0) ^ swz]     = rhu_pack(dxy[0], dxy[1]);
      dst[(4*2560 + b0 + 1) ^ swz] = rhu_pack(dxy[2], dxy[3]);
    }
  };

  __syncthreads();   // gwfrag visible

  UF frag_cur, frag_next;
  *(uint4*)frag_cur.w = *(const uint4*)&sm.gwfrag[0][lane][0];
  vert(frag_cur.v, sm.vfT[0]);
  __syncthreads();

  for (int cb = 0; cb < 25; ++cb) {
    const int PAD = 2 + cb/5;

    // horizontal pass + smap from buf[cb&1]: 5 x b128 at swizzled base
    {
      const unsigned int* V = sm.vfT[cb & 1];
      const bool rok = (r >= PAD) && (r < HW - PAD);
      float accc = 0.f;
      const int C0 = wid*16;
      const int qb = rowbase + wid*8 + 4 + 4*g;   // 16B-aligned pre-swizzle
      UF bx, by, bxx, byy, bxy;
      *(uint4*)bx.w  = *(const uint4*)&V[(0*2560 + qb) ^ swz];
      *(uint4*)by.w  = *(const uint4*)&V[(1*2560 + qb) ^ swz];
      *(uint4*)bxx.w = *(const uint4*)&V[(2*2560 + qb) ^ swz];
      *(uint4*)byy.w = *(const uint4*)&V[(3*2560 + qb) ^ swz];
      *(uint4*)bxy.w = *(const uint4*)&V[(4*2560 + qb) ^ swz];
      f32x4 dhx  = __builtin_amdgcn_mfma_f32_16x16x32_bf16(frag_cur.v, bx.v,  zero4, 0,0,0);
      f32x4 dhy  = __builtin_amdgcn_mfma_f32_16x16x32_bf16(frag_cur.v, by.v,  zero4, 0,0,0);
      f32x4 dhxx = __builtin_amdgcn_mfma_f32_16x16x32_bf16(frag_cur.v, bxx.v, zero4, 0,0,0);
      f32x4 dhyy = __builtin_amdgcn_mfma_f32_16x16x32_bf16(frag_cur.v, byy.v, zero4, 0,0,0);
      f32x4 dhxy = __builtin_amdgcn_mfma_f32_16x16x32_bf16(frag_cur.v, bxy.v, zero4, 0,0,0);
      #pragma unroll
      for (int i = 0; i < 4; ++i) {
        const int c = C0 + g*4 + i;
        if (rok && c >= PAD && c < HW - PAD) {
          const float hx = dhx[i], hy = dhy[i];
          const float hxx = dhxx[i], hyy = dhyy[i], hxy = dhxy[i];
          const float sx = hxx - hx*hx, sy = hyy - hy*hy, sxy = hxy - hx*hy;
          const float num = (2.f*hx*hy + C1f) * (2.f*sxy + C2f);
          const float den = (hx*hx + hy*hy + C1f) * (sx + sy + C2f);
          accc += num * __builtin_amdgcn_rcpf(den);
        }
      }
      const float n1 = (float)(HW - 2*PAD);
      acc_total += accc * __builtin_amdgcn_rcpf(n1 * n1);
    }

    // prefetch next combo's fragment + vertical into the OTHER buffer
    if (cb < 24) {
      *(uint4*)frag_next.w = *(const uint4*)&sm.gwfrag[cb + 1][lane][0];
      vert(frag_next.v, sm.vfT[(cb + 1) & 1]);
    }
    __syncthreads();   // closes: reads of buf[cb&1] AND writes of buf[(cb+1)&1]
    frag_cur = frag_next;
  }

  // block reduction
  sm.red[t] = acc_total;
  __syncthreads();
  for (int off = 512; off > 0; off >>= 1) {
    if (t < off) sm.red[t] += sm.red[t+off];
    __syncthreads();
  }
  if (t == 0) partial[bid] = sm.red[0] * (1.f / (25.f * 128.f));
}

// ---------------- Kernel C: final deterministic reduction ----------------
__global__ __launch_bounds__(256)
void reduce_kernel(const float* __restrict__ partial, float* __restrict__ out)
{
  const int t = threadIdx.x;
  double s = 0.0;
  for (int i = t; i < NBLK; i += 256) s += (double)partial[i];
  __shared__ double red[256];
  red[t] = s;
  __syncthreads();
  for (int off = 128; off > 0; off >>= 1) {
    if (t < off) red[t] += red[t+off];
    __syncthreads();
  }
  if (t == 0) out[0] = (float)(0.5 - 0.5 * red[0]);
}

extern "C" void kernel_launch(void* const* d_in, const int* in_sizes, int n_in,
                              void* d_out, int out_size, void* d_ws, size_t ws_size,
                              hipStream_t stream) {
  const float* pred = (const float*)d_in[0];
  const float* targ = (const float*)d_in[1];
  float* out = (float*)d_out;
  float* ws = (float*)d_ws;
  float* stats   = ws;          // 512 floats
  float* partial = ws + 512;    // NBLK floats

  stats_kernel<<<256, 256, 0, stream>>>(pred, targ, stats);
  ssim_fused<<<NBLK, 1024, 0, stream>>>(pred, targ, stats, partial);
  reduce_kernel<<<1, 256, 0, stream>>>(partial, out);
}